// Round 3
// baseline (375607.544 us; speedup 1.0000x reference)
//
#include <hip/hip_runtime.h>
#include <hip/hip_fp16.h>
#include <cstddef>

typedef unsigned int uint32;

#define B_   32
#define TE_  512
#define TD_  512
#define NM_  80
#define PRE_ 256
#define EH_  512
#define AH_  1024
#define AD_  128

__device__ __forceinline__ float sigf(float x) { return 1.0f / (1.0f + expf(-x)); }

// ---------------- agent-scope (cross-XCD coherent) access helpers ----------------
__device__ __forceinline__ float agl(const float* p) {
  return __hip_atomic_load(p, __ATOMIC_RELAXED, __HIP_MEMORY_SCOPE_AGENT);
}
__device__ __forceinline__ void ags(float* p, float v) {
  __hip_atomic_store(p, v, __ATOMIC_RELAXED, __HIP_MEMORY_SCOPE_AGENT);
}

// Hand-rolled grid barrier: 2-level monotonic counter tree, relaxed agent atomics
// only — NO acquire/release fence, so no L2 invalidate / writeback ever executes.
__device__ __forceinline__ void gsync(uint32* bar, unsigned bep) {
  __syncthreads();
  if (threadIdx.x == 0) {
    asm volatile("s_waitcnt vmcnt(0)" ::: "memory");
    uint32* leaf = bar + (blockIdx.x >> 5) * 32;   // 8 leaves x 32 blocks, line-spaced
    uint32* root = bar + 256;
    uint32 prev = __hip_atomic_fetch_add(leaf, 1u, __ATOMIC_RELAXED, __HIP_MEMORY_SCOPE_AGENT);
    if (prev + 1u == 32u * bep)
      __hip_atomic_fetch_add(root, 1u, __ATOMIC_RELAXED, __HIP_MEMORY_SCOPE_AGENT);
    int spins = 0;
    while (__hip_atomic_load(root, __ATOMIC_RELAXED, __HIP_MEMORY_SCOPE_AGENT) < 8u * bep) {
      __builtin_amdgcn_s_sleep(2);
      if (++spins > 20000000) break;   // safety valve: fail instead of hang
    }
  }
  __syncthreads();
}

// sum over each 16-lane row via DPP (VALU pipe, no LDS)
__device__ __forceinline__ float rowsum16(float v) {
  int vi;
  vi = __float_as_int(v);
  v += __int_as_float(__builtin_amdgcn_update_dpp(0, vi, 0xB1, 0xF, 0xF, true));  // quad xor1
  vi = __float_as_int(v);
  v += __int_as_float(__builtin_amdgcn_update_dpp(0, vi, 0x4E, 0xF, 0xF, true));  // quad xor2
  vi = __float_as_int(v);
  v += __int_as_float(__builtin_amdgcn_update_dpp(0, vi, 0x124, 0xF, 0xF, true)); // row_ror:4
  vi = __float_as_int(v);
  v += __int_as_float(__builtin_amdgcn_update_dpp(0, vi, 0x128, 0xF, 0xF, true)); // row_ror:8
  return v;
}

// ---------------- prologue: LSTM weight packing (fp16, LDS-resident layouts) ----
__global__ __launch_bounds__(256) void k_pack_lstm2(
    const float* __restrict__ awih, const float* __restrict__ awhh,
    const float* __restrict__ dwih, const float* __restrict__ dwhh,
    uint32* __restrict__ wal, uint32* __restrict__ wdl, uint32* __restrict__ wdt)
{
  long gid = blockIdx.x * 256L + threadIdx.x;
  const long N1 = 3686400L, N2 = 4603904L, N3 = 655360L;
  if (gid < N1) {
    int blk = (int)(gid / 28800), rem = (int)(gid % 28800);
    int r2 = rem % 900;
    int ks = rem / 900;
    uint32 out = 0;
    if (r2 < 896) {
      int kq = r2 >> 4, rd = r2 & 15;
      int k = kq * 32 + ks;
      int rp0 = blk * 32 + 2 * rd, rp1 = rp0 + 1;
      int row0 = (rp0 & 3) * 1024 + (rp0 >> 2);
      int row1 = (rp1 & 3) * 1024 + (rp1 >> 2);
      float w0 = (k < 768) ? awih[(size_t)row0 * 768 + k] : awhh[(size_t)row0 * 1024 + k - 768];
      float w1 = (k < 768) ? awih[(size_t)row1 * 768 + k] : awhh[(size_t)row1 * 1024 + k - 768];
      __half2 h = __floats2half2_rn(w0, w1);
      out = *(uint32*)&h;
    }
    wal[gid] = out;
  } else if (gid < N1 + N2) {
    long g = gid - N1;
    int blk = (int)(g / 35968), rem = (int)(g % 35968);
    int r2 = rem % 1124;
    int ks = rem / 1124;
    uint32 out = 0;
    if (r2 < 1120) {
      int kq = r2 >> 4, rd = r2 & 15;
      int k = kq * 32 + ks;
      int rp0 = blk * 32 + 2 * rd, rp1 = rp0 + 1;
      int row0 = (rp0 & 3) * 1024 + (rp0 >> 2);
      int row1 = (rp1 & 3) * 1024 + (rp1 >> 2);
      float w0 = (k < 1536) ? dwih[(size_t)row0 * 1536 + k] : dwhh[(size_t)row0 * 1024 + k - 1536];
      float w1 = (k < 1536) ? dwih[(size_t)row1 * 1536 + k] : dwhh[(size_t)row1 * 1024 + k - 1536];
      __half2 h = __floats2half2_rn(w0, w1);
      out = *(uint32*)&h;
    }
    wdl[g] = out;
  } else if (gid < N1 + N2 + N3) {
    long g = gid - N1 - N2;
    int blk = (int)(g / 5120), rem = (int)(g % 5120);
    int rd2 = rem & 3, rg = (rem >> 2) & 3, ks = (rem >> 4) & 31, i = rem >> 9;
    int k = 2240 + 32 * i + ks;
    int r0 = rg * 8 + 2 * rd2;
    int rp0 = blk * 32 + r0, rp1 = rp0 + 1;
    int row0 = (rp0 & 3) * 1024 + (rp0 >> 2);
    int row1 = (rp1 & 3) * 1024 + (rp1 >> 2);
    float w0 = (k < 1536) ? dwih[(size_t)row0 * 1536 + k] : dwhh[(size_t)row0 * 1024 + k - 1536];
    float w1 = (k < 1536) ? dwih[(size_t)row1 * 1536 + k] : dwhh[(size_t)row1 * 1024 + k - 1536];
    __half2 h = __floats2half2_rn(w0, w1);
    wdt[g] = *(uint32*)&h;
  }
}

__global__ __launch_bounds__(256) void k_pack_small(
    const float* __restrict__ w1, const float* __restrict__ w2,
    const float* __restrict__ mw, const float* __restrict__ pw,
    const float* __restrict__ abih, const float* __restrict__ abhh,
    const float* __restrict__ dbih, const float* __restrict__ dbhh,
    const float* __restrict__ lw, const float* __restrict__ cw,
    float* __restrict__ w1t, float* __restrict__ w2t, float* __restrict__ mt,
    float* __restrict__ pjt, float* __restrict__ ba, float* __restrict__ bd,
    float* __restrict__ lc)
{
  int gid = blockIdx.x * 256 + threadIdx.x;
  if (gid < 20480) { int k = gid / 256, j = gid % 256; w1t[gid] = w1[j * 80 + k]; return; }
  gid -= 20480;
  if (gid < 65536) { int k = gid / 256, j = gid % 256; w2t[gid] = w2[j * 256 + k]; return; }
  gid -= 65536;
  if (gid < 65536) { int e = gid / 128, d = gid % 128; mt[gid] = mw[d * 512 + e]; return; }
  gid -= 65536;
  if (gid < 122880) { int k = gid / 80, m = gid % 80; pjt[gid] = pw[m * 1536 + k]; return; }
  gid -= 122880;
  if (gid < 4096) { int j = gid >> 2, g = gid & 3, row = g * 1024 + j; ba[gid] = abih[row] + abhh[row]; return; }
  gid -= 4096;
  if (gid < 4096) { int j = gid >> 2, g = gid & 3, row = g * 1024 + j; bd[gid] = dbih[row] + dbhh[row]; return; }
  gid -= 4096;
  if (gid < 7936) {
    int c = gid / (31 * 128), rem = gid % (31 * 128);
    int kk = rem / 128, d = rem % 128;
    float s = 0.f;
    for (int f = 0; f < 32; ++f) s += lw[d * 32 + f] * cw[(f * 2 + c) * 31 + kk];
    lc[gid] = s;
  }
}

// ---------------- prologue: prenet (verified) ----------------
__global__ __launch_bounds__(256) void k_prenet(
    const float* __restrict__ targets, const float* __restrict__ w1t,
    const float* __restrict__ b1, const float* __restrict__ w2t,
    const float* __restrict__ b2, float* __restrict__ pn)
{
  int t = blockIdx.x, tid = threadIdx.x;
  __shared__ float X[32][80];
  __shared__ float h1[256][33];
  for (int i = tid; i < 2560; i += 256) {
    int b = i / 80, m = i % 80;
    X[b][m] = (t == 0) ? 0.f : targets[((size_t)b * TD_ + (t - 1)) * NM_ + m];
  }
  __syncthreads();
  int j = tid;
  float bj = b1[j];
  for (int bt = 0; bt < 4; ++bt) {
    float acc[8];
#pragma unroll
    for (int i = 0; i < 8; ++i) acc[i] = bj;
    for (int k = 0; k < 80; ++k) {
      float w = w1t[k * 256 + j];
#pragma unroll
      for (int i = 0; i < 8; ++i) acc[i] += w * X[bt * 8 + i][k];
    }
#pragma unroll
    for (int i = 0; i < 8; ++i) h1[j][bt * 8 + i] = fmaxf(acc[i], 0.f);
  }
  __syncthreads();
  float cj = b2[j];
  float* out = pn + (size_t)t * PRE_ * B_;
  for (int bt = 0; bt < 4; ++bt) {
    float acc[8];
#pragma unroll
    for (int i = 0; i < 8; ++i) acc[i] = cj;
    for (int k = 0; k < 256; ++k) {
      float w = w2t[k * 256 + j];
#pragma unroll
      for (int i = 0; i < 8; ++i) acc[i] += w * h1[k][bt * 8 + i];
    }
#pragma unroll
    for (int i = 0; i < 8; ++i) out[j * 32 + bt * 8 + i] = fmaxf(acc[i], 0.f);
  }
}

// ---------------- prologue: processed_enc (verified) ----------------
__global__ __launch_bounds__(256) void k_penc(
    const float* __restrict__ enc, const float* __restrict__ mt,
    float* __restrict__ penc)
{
  int t = blockIdx.x, tid = threadIdx.x;
  __shared__ float encL[32][256];
  __shared__ float red[128][8][2];
  int d = tid & 127, s = tid >> 7;
  float acc[4][8];
#pragma unroll
  for (int bt = 0; bt < 4; ++bt)
#pragma unroll
    for (int i = 0; i < 8; ++i) acc[bt][i] = 0.f;
  for (int eh = 0; eh < 2; ++eh) {
    for (int i = tid; i < 8192; i += 256) {
      int b = i >> 8, e = i & 255;
      encL[b][e] = enc[((size_t)b * TE_ + t) * EH_ + eh * 256 + e];
    }
    __syncthreads();
    for (int bt = 0; bt < 4; ++bt) {
      for (int el = s * 128; el < s * 128 + 128; ++el) {
        float w = mt[(eh * 256 + el) * 128 + d];
#pragma unroll
        for (int i = 0; i < 8; ++i) acc[bt][i] += w * encL[bt * 8 + i][el];
      }
    }
    __syncthreads();
  }
  for (int bt = 0; bt < 4; ++bt) {
#pragma unroll
    for (int i = 0; i < 8; ++i) red[d][i][s] = acc[bt][i];
    __syncthreads();
    if (s == 0) {
#pragma unroll
      for (int i = 0; i < 8; ++i)
        penc[((size_t)t * AD_ + d) * 32 + bt * 8 + i] = red[d][i][0] + red[d][i][1];
    }
    __syncthreads();
  }
}

// ---------------- prologue: enc transpose to fp16 [b][e][t] ----------------
__global__ __launch_bounds__(256) void k_enct(
    const float* __restrict__ enc, __half* __restrict__ enct)
{
  int blk = blockIdx.x, tid = threadIdx.x;
  int b = blk >> 6, t0 = ((blk >> 3) & 7) * 64, e0 = (blk & 7) * 64;
  __shared__ float tile[64][65];
  for (int i = 0; i < 16; ++i) {
    int tl = i * 4 + (tid >> 6), e = tid & 63;
    tile[tl][e] = enc[((size_t)b * TE_ + t0 + tl) * EH_ + e0 + e];
  }
  __syncthreads();
  for (int i = 0; i < 16; ++i) {
    int el = i * 4 + (tid >> 6), tl = tid & 63;
    enct[((size_t)b * EH_ + e0 + el) * TE_ + t0 + tl] = __float2half(tile[tl][el]);
  }
}

// ---------------- persistent step kernel ----------------
struct KP {
  const uint32* wal; const uint32* wdl; const uint4* wdt;
  const float* pn; const float* penc; const __half* enct;
  const float* qw; const float* ww; const float* pjt; const float* pjb;
  const float* lc; const float* ba; const float* bd;
  float* ahv; float* ac; float* dhv; float* dc; float* ctxv; float* aw; float* aws;
  float* enp; float* mel; float* align;
  uint32* bar; int pv;
};

__device__ __forceinline__ void fma2(uint4 wv, const float* __restrict__ XC,
                                     int xb, float* acc)
{
  const __half2* hp = (const __half2*)&wv;
  float w[8];
#pragma unroll
  for (int d = 0; d < 4; ++d) {
    float2 f = __half22float2(hp[d]);
    w[2 * d] = f.x; w[2 * d + 1] = f.y;
  }
  float4 xa = *(const float4*)&XC[xb];
  float4 xc2 = *(const float4*)&XC[xb + 4];
  float x[8] = {xa.x, xa.y, xa.z, xa.w, xc2.x, xc2.y, xc2.z, xc2.w};
#pragma unroll
  for (int ri = 0; ri < 8; ++ri)
#pragma unroll
    for (int bi = 0; bi < 8; ++bi)
      acc[ri * 8 + bi] = fmaf(w[ri], x[bi], acc[ri * 8 + bi]);
}

__device__ __forceinline__ void lstm_finish(
    float* acc, float* __restrict__ GT, const float* __restrict__ bias,
    float* __restrict__ cst, float* __restrict__ hout,
    int rp0, int tid, int ks, int bq, int rg)
{
#pragma unroll
  for (int i = 0; i < 64; ++i) {
    float v = rowsum16(acc[i]);
    acc[i] = v + __shfl_xor(v, 16);
  }
  if (ks == 0) {
#pragma unroll
    for (int ri = 0; ri < 8; ++ri) {
      *(float4*)&GT[(rg * 8 + ri) * 32 + bq * 8] =
          make_float4(acc[ri * 8 + 0], acc[ri * 8 + 1], acc[ri * 8 + 2], acc[ri * 8 + 3]);
      *(float4*)&GT[(rg * 8 + ri) * 32 + bq * 8 + 4] =
          make_float4(acc[ri * 8 + 4], acc[ri * 8 + 5], acc[ri * 8 + 6], acc[ri * 8 + 7]);
    }
  }
  __syncthreads();
  if (tid < 256) {
    int jl = tid >> 5, b = tid & 31;
    float gi = GT[(jl * 4 + 0) * 32 + b] + bias[rp0 + jl * 4 + 0];
    float gf = GT[(jl * 4 + 1) * 32 + b] + bias[rp0 + jl * 4 + 1];
    float gg = GT[(jl * 4 + 2) * 32 + b] + bias[rp0 + jl * 4 + 2];
    float go = GT[(jl * 4 + 3) * 32 + b] + bias[rp0 + jl * 4 + 3];
    int j = (rp0 >> 2) + jl;
    float c0 = cst[j * 32 + b];                 // block-private: plain cached r/w
    float c2 = sigf(gf) * c0 + sigf(gi) * tanhf(gg);
    float h2 = sigf(go) * tanhf(c2);
    cst[j * 32 + b] = c2;
    ags(&hout[j * 32 + b], h2);                 // communicated: write-through to L3
  }
}

// A-LSTM: 28 chunks, 7-deep register prefetch pipeline (statically indexed).
__device__ __forceinline__ void run_lstm_a(const KP& p, int t,
    const float* __restrict__ ah_in, const float* __restrict__ ctx_in,
    float* __restrict__ ah_out,
    uint32* WlU, float* XC, float* GT, int tid, int ks, int bq, int rg,
    int kidx, int b4, int blk)
{
  float acc[64];
#pragma unroll
  for (int i = 0; i < 64; ++i) acc[i] = 0.f;
  const float* xp0 = p.pn + (size_t)t * 8192;
  const float* xp1 = ctx_in;
  const float* xp2 = ah_in;
  const int wb = ks * 900 + rg * 4;
  const int xr = ks * 36 + bq * 8;
  float4 st[7];
#pragma unroll
  for (int u = 0; u < 7; ++u) {
    int kg = u * 64 + kidx;
    const float* src = (kg < 256) ? xp0 + (size_t)kg * 32
                     : (kg < 768) ? xp1 + (size_t)(kg - 256) * 32
                                  : xp2 + (size_t)(kg - 768) * 32;
    st[u] = *(const float4*)(src + b4);
  }
  for (int cb = 0; cb < 28; cb += 7) {
#pragma unroll
    for (int u = 0; u < 7; ++u) {
      const int c = cb + u;
      __syncthreads();
      *(float4*)&XC[kidx * 36 + b4] = st[u];
      __syncthreads();
      const int cn = c + 7;
      if (cn < 28) {
        int kg = cn * 64 + kidx;
        const float* src = (kg < 256) ? xp0 + (size_t)kg * 32
                         : (kg < 768) ? xp1 + (size_t)(kg - 256) * 32
                                      : xp2 + (size_t)(kg - 768) * 32;
        st[u] = *(const float4*)(src + b4);
      }
      fma2(*(const uint4*)&WlU[wb + (2 * c) * 16], XC, xr, acc);
      fma2(*(const uint4*)&WlU[wb + (2 * c + 1) * 16], XC, xr + 32 * 36, acc);
    }
  }
  lstm_finish(acc, GT, p.ba, p.ac, ah_out, blk * 32, tid, ks, bq, rg);
}

// D-LSTM: 40 chunks = 32 main (8-deep pipeline) + 8 static tail (3 LDS + 5 VGPR wt).
__device__ __forceinline__ void run_lstm_d(const KP& p,
    const float* __restrict__ xp0, const float* __restrict__ xp1,
    const float* __restrict__ xp2, float* __restrict__ dh_w,
    uint32* WlU, float* XC, float* GT, const uint4* wt,
    int tid, int ks, int bq, int rg, int kidx, int b4, int blk)
{
  float acc[64];
#pragma unroll
  for (int i = 0; i < 64; ++i) acc[i] = 0.f;
  const int wb = ks * 1124 + rg * 4;
  const int xr = ks * 36 + bq * 8;
  float4 st[8];
#pragma unroll
  for (int u = 0; u < 8; ++u) {
    int kg = u * 64 + kidx;
    const float* src = (kg < 1024) ? xp0 + (size_t)kg * 32
                     : (kg < 1536) ? xp1 + (size_t)(kg - 1024) * 32
                                   : xp2 + (size_t)(kg - 1536) * 32;
    st[u] = *(const float4*)(src + b4);
  }
  for (int cb = 0; cb < 32; cb += 8) {
#pragma unroll
    for (int u = 0; u < 8; ++u) {
      const int c = cb + u;
      __syncthreads();
      *(float4*)&XC[kidx * 36 + b4] = st[u];
      __syncthreads();
      const int cn = c + 8;  // <= 39 always
      {
        int kg = cn * 64 + kidx;
        const float* src = (kg < 1024) ? xp0 + (size_t)kg * 32
                         : (kg < 1536) ? xp1 + (size_t)(kg - 1024) * 32
                                       : xp2 + (size_t)(kg - 1536) * 32;
        st[u] = *(const float4*)(src + b4);
      }
      fma2(*(const uint4*)&WlU[wb + (2 * c) * 16], XC, xr, acc);
      fma2(*(const uint4*)&WlU[wb + (2 * c + 1) * 16], XC, xr + 32 * 36, acc);
    }
  }
  // tail: chunks 32..39 already prefetched in st[0..7]; static indices for wt[]
#pragma unroll
  for (int u = 0; u < 8; ++u) {
    const int c = 32 + u;
    __syncthreads();
    *(float4*)&XC[kidx * 36 + b4] = st[u];
    __syncthreads();
    if (c < 35) {
      fma2(*(const uint4*)&WlU[wb + (2 * c) * 16], XC, xr, acc);
      fma2(*(const uint4*)&WlU[wb + (2 * c + 1) * 16], XC, xr + 32 * 36, acc);
    } else {
      fma2(wt[2 * (c - 35)], XC, xr, acc);
      fma2(wt[2 * (c - 35) + 1], XC, xr + 32 * 36, acc);
    }
  }
  lstm_finish(acc, GT, p.bd, p.dc, dh_w, (blk - 128) * 32, tid, ks, bq, rg);
}

__device__ __forceinline__ void mel_block(
    const float* __restrict__ dhp, const float* __restrict__ ctp,
    const float* __restrict__ pjt, const float* __restrict__ pjb,
    float* __restrict__ mel, int bb, int tt, float* S, int tid)
{
  float* xo = S + 1536;
  float* ro = S + 3072;
  for (int i = tid; i < 1536; i += 512)
    xo[i] = (i < 1024) ? dhp[i * 32 + bb] : ctp[(i - 1024) * 32 + bb];
  __syncthreads();
  if (tid < 480) {
    int m = tid % 80, k2 = tid / 80;
    float a2 = 0.f;
    for (int k = k2 * 256; k < k2 * 256 + 256; ++k) a2 += pjt[k * 80 + m] * xo[k];
    ro[m * 8 + k2] = a2;
  }
  __syncthreads();
  if (tid < 80) {
    float s3 = pjb[tid];
#pragma unroll
    for (int k = 0; k < 6; ++k) s3 += ro[tid * 8 + k];
    mel[((size_t)bb * TD_ + tt) * NM_ + tid] = s3;
  }
}

__global__ __launch_bounds__(512, 2) void k_step(KP p)
{
  extern __shared__ float LDSF[];
  const int blk = blockIdx.x, tid = threadIdx.x;
  const int ks = tid & 31, bq = (tid >> 5) & 3, rg = tid >> 7;
  const int kidx = tid >> 3, b4 = (tid & 7) * 4;
  const bool isA = blk < 128;
  float* SC = LDSF + (isA ? 28800 : 35968);
  float* XC = SC;
  float* GT = SC + 2304;
  uint32* WlU = (uint32*)LDSF;
  unsigned bep = 0;

  // one-time: weights into LDS (+VGPR tail for D)
  {
    const uint32* src = isA ? p.wal + (size_t)blk * 28800
                            : p.wdl + (size_t)(blk - 128) * 35968;
    int n4 = isA ? 7200 : 8992;
    for (int i = tid; i < n4; i += 512)
      ((uint4*)WlU)[i] = ((const uint4*)src)[i];
  }
  uint4 wt[10];
  if (!isA) {
#pragma unroll
    for (int i = 0; i < 10; ++i)
      wt[i] = p.wdt[(size_t)(blk - 128) * 1280 + (i * 32 + ks) * 4 + rg];
  }
  __syncthreads();

  for (int t = 0; t < TD_; ++t) {
    // version slots: slot ver(s)=s%pv holds state INPUT to step s (written at s-1)
    const int vc = t % p.pv;
    const int vn = (t + 1) % p.pv;
    const int vp = (t > 0) ? (t - 1) % p.pv : 0;
    const float* ah_in  = p.ahv + (size_t)vc * 32768;
    float*       ah_out = p.ahv + (size_t)vn * 32768;
    const float* ctx_in = p.ctxv + (size_t)vc * 16384;
    float*       ctx_out= p.ctxv + (size_t)vn * 16384;

    // ---- PA: lstm_a(t) [0..127] || lstm_d(t-1) [128..255] ----
    if (isA) {
      run_lstm_a(p, t, ah_in, ctx_in, ah_out, WlU, XC, GT, tid, ks, bq, rg, kidx, b4, blk);
    } else if (t > 0) {
      run_lstm_d(p, ah_in, ctx_in,
                 p.dhv + (size_t)vp * 32768, p.dhv + (size_t)vc * 32768,
                 WlU, XC, GT, wt, tid, ks, bq, rg, kidx, b4, blk);
    }
    bep += 1; gsync(p.bar, bep);
    // ---- PB: q (from ah slot vn) + location conv + energies ----
    {
      int tc = blk >> 3, ds = blk & 7;
      int t0 = tc * 16, d0 = ds * 16;
      float* qs  = SC;            // 512
      float* wws = SC + 512;      // 16
      float* AHC = SC + 528;      // 2048 (chunk buffer, later reused by win/lcs)
      float* win = SC + 528;      // 2944
      float* lcs = SC + 528 + 2944; // 992

      // early issue: win (agl), lcs, penc, ww — all into registers, hidden under q-loop
      float winr[6];
#pragma unroll
      for (int k = 0; k < 6; ++k) {
        int i = tid + k * 512;
        float v = 0.f;
        if (i < 2944) {
          int c = i / 1472, r = (i >> 5) % 46, bbw = i & 31;
          int tg = t0 - 15 + r;
          if (tg >= 0 && tg < 512) v = agl((c ? p.aws : p.aw) + tg * 32 + bbw);
        }
        winr[k] = v;
      }
      float lcr[2];
#pragma unroll
      for (int k = 0; k < 2; ++k) {
        int i = tid + k * 512;
        lcr[k] = 0.f;
        if (i < 992) {
          int c = i / 496, kk = (i >> 4) % 31, dl2 = i & 15;
          lcr[k] = p.lc[(c * 31 + kk) * 128 + d0 + dl2];
        }
      }
      const int bbE = tid & 31, thE = tid >> 5;
      const int ttE = t0 + thE;
      float pencr[16];
#pragma unroll
      for (int dl2 = 0; dl2 < 16; ++dl2)
        pencr[dl2] = p.penc[((size_t)ttE * 128 + d0 + dl2) * 32 + bbE];
      float wwr = (tid < 16) ? p.ww[d0 + tid] : 0.f;

      // q: 16-chunk LDS-staged matvec, 8-deep prefetch
      int bb2 = tid & 31, dl = tid >> 5;
      const float* ahsrc = p.ahv + (size_t)vn * 32768;
      const float* qbase = p.qw + (size_t)(d0 + dl) * 1024;
      float qacc = 0.f;
      float4 stq[8];
#pragma unroll
      for (int u = 0; u < 8; ++u) stq[u] = *(const float4*)(ahsrc + u * 2048 + tid * 4);
      for (int cb = 0; cb < 16; cb += 8) {
#pragma unroll
        for (int u = 0; u < 8; ++u) {
          const int ch = cb + u;
          __syncthreads();
          *(float4*)(AHC + tid * 4) = stq[u];
          __syncthreads();
          const int chn = ch + 8;
          if (chn < 16) stq[u] = *(const float4*)(ahsrc + chn * 2048 + tid * 4);
          const float* qrow = qbase + ch * 64;
#pragma unroll
          for (int jj = 0; jj < 64; jj += 4) {
            float4 qv = *(const float4*)(qrow + jj);
            qacc = fmaf(qv.x, AHC[(jj + 0) * 32 + bb2], qacc);
            qacc = fmaf(qv.y, AHC[(jj + 1) * 32 + bb2], qacc);
            qacc = fmaf(qv.z, AHC[(jj + 2) * 32 + bb2], qacc);
            qacc = fmaf(qv.w, AHC[(jj + 3) * 32 + bb2], qacc);
          }
        }
      }
      __syncthreads();
      qs[dl * 32 + bb2] = qacc;
      if (tid < 16) wws[tid] = wwr;
#pragma unroll
      for (int k = 0; k < 6; ++k) { int i = tid + k * 512; if (i < 2944) win[i] = winr[k]; }
#pragma unroll
      for (int k = 0; k < 2; ++k) { int i = tid + k * 512; if (i < 992) lcs[i] = lcr[k]; }
      __syncthreads();
      {
        float pa[16];
#pragma unroll
        for (int i = 0; i < 16; ++i) pa[i] = 0.f;
        for (int c = 0; c < 2; ++c) {
          for (int kk = 0; kk < 31; ++kk) {
            float wv = win[c * 1472 + (thE + kk) * 32 + bbE];
            const float4* lr = (const float4*)(lcs + c * 496 + kk * 16);
            float4 l0 = lr[0], l1 = lr[1], l2 = lr[2], l3 = lr[3];
            pa[0]  += l0.x * wv; pa[1]  += l0.y * wv; pa[2]  += l0.z * wv; pa[3]  += l0.w * wv;
            pa[4]  += l1.x * wv; pa[5]  += l1.y * wv; pa[6]  += l1.z * wv; pa[7]  += l1.w * wv;
            pa[8]  += l2.x * wv; pa[9]  += l2.y * wv; pa[10] += l2.z * wv; pa[11] += l2.w * wv;
            pa[12] += l3.x * wv; pa[13] += l3.y * wv; pa[14] += l3.z * wv; pa[15] += l3.w * wv;
          }
        }
        float epv = 0.f;
#pragma unroll
        for (int dl2 = 0; dl2 < 16; ++dl2) {
          float v = qs[dl2 * 32 + bbE] + pencr[dl2] + pa[dl2];
          epv += wws[dl2] * tanhf(v);
        }
        ags(&p.enp[(size_t)bbE * 4096 + ttE * 8 + ds], epv);
      }
    }
    bep += 1; gsync(p.bar, bep);
    // ---- PC: softmax + ctx (+aw/aws/align, +mel(t-1)) ----
    {
      int bb = blk >> 3, et = blk & 7;
      float* awL = SC + 512;
      float* cr  = SC + 1024;
      // early: prefetch the 64x64-half enct tile into registers (before softmax)
      int el = tid & 63, ts = tid >> 6;
      const uint32* eb = (const uint32*)(p.enct +
          ((size_t)(bb * 512 + et * 64 + el)) * 512 + ts * 64);
      uint32 ebr[32];
#pragma unroll
      for (int i = 0; i < 32; ++i) ebr[i] = eb[i];
      const float* epb = p.enp + (size_t)bb * 4096 + tid * 8;
      float e = agl(epb) + agl(epb + 1) + agl(epb + 2) + agl(epb + 3)
              + agl(epb + 4) + agl(epb + 5) + agl(epb + 6) + agl(epb + 7);
      // softmax: wave shfl reduce + 8-wave LDS combine (2 barriers total)
      float m = e;
#pragma unroll
      for (int k = 1; k < 64; k <<= 1) m = fmaxf(m, __shfl_xor(m, k));
      int wv = tid >> 6;
      if ((tid & 63) == 0) SC[wv] = m;
      __syncthreads();
      m = SC[0];
#pragma unroll
      for (int k = 1; k < 8; ++k) m = fmaxf(m, SC[k]);
      float x = expf(e - m);
      float s = x;
#pragma unroll
      for (int k = 1; k < 64; k <<= 1) s += __shfl_xor(s, k);
      if ((tid & 63) == 0) SC[8 + wv] = s;
      __syncthreads();
      s = SC[8];
#pragma unroll
      for (int k = 1; k < 8; ++k) s += SC[8 + k];
      float a = x * (1.f / s);
      awL[tid] = a;
      __syncthreads();
      float acc = 0.f;
#pragma unroll
      for (int i = 0; i < 32; ++i) {
        float2 f = __half22float2(*(const __half2*)&ebr[i]);
        acc += awL[ts * 64 + 2 * i] * f.x + awL[ts * 64 + 2 * i + 1] * f.y;
      }
      cr[ts * 64 + el] = acc;
      __syncthreads();
      if (tid < 64) {
        float s2 = 0.f;
#pragma unroll
        for (int k = 0; k < 8; ++k) s2 += cr[k * 64 + tid];
        ags(&ctx_out[(et * 64 + tid) * 32 + bb], s2);
      }
      if (et == 0) {
        ags(&p.aw[tid * 32 + bb], a);
        float os = agl(&p.aws[tid * 32 + bb]);
        ags(&p.aws[tid * 32 + bb], os + a);
        p.align[((size_t)bb * TD_ + t) * TE_ + tid] = a;
      }
      if (et == 1 && t > 0) {
        mel_block(p.dhv + (size_t)vc * 32768, p.ctxv + (size_t)vc * 16384,
                  p.pjt, p.pjb, p.mel, bb, t - 1, SC, tid);
      }
    }
    bep += 1; gsync(p.bar, bep);
  }
  // ---- epilogue: lstm_d(511) then mel(511) ----
  {
    const int v511 = 511 % p.pv, v512 = 512 % p.pv;
    if (!isA) {
      run_lstm_d(p, p.ahv + (size_t)v512 * 32768, p.ctxv + (size_t)v512 * 16384,
                 p.dhv + (size_t)v511 * 32768, p.dhv + (size_t)v512 * 32768,
                 WlU, XC, GT, wt, tid, ks, bq, rg, kidx, b4, blk);
    }
    bep += 1; gsync(p.bar, bep);
    if (blk < 32) {
      mel_block(p.dhv + (size_t)v512 * 32768, p.ctxv + (size_t)v512 * 16384,
                p.pjt, p.pjb, p.mel, blk, 511, SC, tid);
    }
  }
}

extern "C" void kernel_launch(void* const* d_in, const int* in_sizes, int n_in,
                              void* d_out, int out_size, void* d_ws, size_t ws_size,
                              hipStream_t stream)
{
  const float* enc     = (const float*)d_in[0];
  const float* targets = (const float*)d_in[1];
  const float* pw1  = (const float*)d_in[2];
  const float* pb1  = (const float*)d_in[3];
  const float* pw2  = (const float*)d_in[4];
  const float* pb2  = (const float*)d_in[5];
  const float* mw   = (const float*)d_in[6];
  const float* qw   = (const float*)d_in[7];
  const float* www  = (const float*)d_in[8];
  const float* lw   = (const float*)d_in[9];
  const float* cw   = (const float*)d_in[10];
  const float* awih = (const float*)d_in[11];
  const float* awhh = (const float*)d_in[12];
  const float* abih = (const float*)d_in[13];
  const float* abhh = (const float*)d_in[14];
  const float* dwih = (const float*)d_in[15];
  const float* dwhh = (const float*)d_in[16];
  const float* dbih = (const float*)d_in[17];
  const float* dbhh = (const float*)d_in[18];
  const float* pjw  = (const float*)d_in[19];
  const float* pjb  = (const float*)d_in[20];

  uint32* wsb = (uint32*)d_ws;
  size_t o = 0;
  auto F = [&](size_t n) { size_t r = o; o += n; return r; };
  size_t oWAL = F(3686400), oWDL = F(4603904), oWDT = F(655360);
  size_t oENCT = F(4194304);           // 8,388,608 halfs
  size_t oPN = F(4194304), oPENC = F(2097152);
  size_t oW1T = F(20480), oW2T = F(65536), oMT = F(65536), oPJT = F(122880);
  size_t oLC = F(7936), oBA = F(4096), oBD = F(4096);
  size_t oZR = o;                      // zeroed region start
  size_t oAC = F(32768), oDC = F(32768), oAW = F(16384), oAWS = F(16384), oBAR = F(1024);
  size_t zr_dw = o - oZR;
  o = (o + 31) & ~(size_t)31;          // 128B-align versioned space (line isolation)
  size_t fixed_dw = o;
  size_t avail_dw = ws_size / 4;
  long pvl = (avail_dw > fixed_dw) ? (long)((avail_dw - fixed_dw) / 81920) : 0;
  int pv = (pvl < 3) ? 3 : (pvl > 513 ? 513 : (int)pvl);
  size_t oAHV = F((size_t)pv * 32768);
  size_t oDHV = F((size_t)pv * 32768);
  size_t oCTXV = F((size_t)pv * 16384);
  size_t oENP = oW1T;                  // alias: 131,072 <= 151,552 (W1T+W2T+MT)

  hipMemsetAsync(wsb + oZR, 0, zr_dw * 4, stream);
  hipMemsetAsync(wsb + oAHV, 0, (size_t)32768 * 4, stream);
  hipMemsetAsync(wsb + oDHV, 0, (size_t)32768 * 4, stream);
  hipMemsetAsync(wsb + oCTXV, 0, (size_t)16384 * 4, stream);

  float* mel = (float*)d_out;
  float* align = mel + (size_t)B_ * TD_ * NM_;

  k_pack_lstm2<<<34944, 256, 0, stream>>>(awih, awhh, dwih, dwhh,
                                          wsb + oWAL, wsb + oWDL, wsb + oWDT);
  k_pack_small<<<1135, 256, 0, stream>>>(pw1, pw2, mw, pjw, abih, abhh, dbih, dbhh,
                                         lw, cw,
                                         (float*)(wsb + oW1T), (float*)(wsb + oW2T),
                                         (float*)(wsb + oMT), (float*)(wsb + oPJT),
                                         (float*)(wsb + oBA), (float*)(wsb + oBD),
                                         (float*)(wsb + oLC));
  k_prenet<<<512, 256, 0, stream>>>(targets, (float*)(wsb + oW1T), pb1,
                                    (float*)(wsb + oW2T), pb2, (float*)(wsb + oPN));
  k_penc<<<512, 256, 0, stream>>>(enc, (float*)(wsb + oMT), (float*)(wsb + oPENC));
  k_enct<<<2048, 256, 0, stream>>>(enc, (__half*)(wsb + oENCT));

  KP kp;
  kp.wal = wsb + oWAL; kp.wdl = wsb + oWDL; kp.wdt = (const uint4*)(wsb + oWDT);
  kp.pn = (float*)(wsb + oPN); kp.penc = (float*)(wsb + oPENC);
  kp.enct = (__half*)(wsb + oENCT);
  kp.qw = qw; kp.ww = www; kp.pjt = (float*)(wsb + oPJT); kp.pjb = pjb;
  kp.lc = (float*)(wsb + oLC); kp.ba = (float*)(wsb + oBA); kp.bd = (float*)(wsb + oBD);
  kp.ahv = (float*)(wsb + oAHV); kp.ac = (float*)(wsb + oAC);
  kp.dhv = (float*)(wsb + oDHV); kp.dc = (float*)(wsb + oDC);
  kp.ctxv = (float*)(wsb + oCTXV);
  kp.aw = (float*)(wsb + oAW); kp.aws = (float*)(wsb + oAWS);
  kp.enp = (float*)(wsb + oENP); kp.mel = mel; kp.align = align;
  kp.bar = wsb + oBAR; kp.pv = pv;

  hipFuncSetAttribute((const void*)k_step,
                      hipFuncAttributeMaxDynamicSharedMemorySize, 161728);
  void* kargs[] = { &kp };
  hipLaunchCooperativeKernel((const void*)k_step, dim3(256), dim3(512), kargs,
                             161728, stream);
}

// Round 4
// 97262.921 us; speedup vs baseline: 3.8618x; 3.8618x over previous
//
#include <hip/hip_runtime.h>
#include <hip/hip_fp16.h>
#include <cstddef>

typedef unsigned int uint32;

#define B_   32
#define TE_  512
#define TD_  512
#define NM_  80
#define PRE_ 256
#define EH_  512
#define AH_  1024
#define AD_  128

__device__ __forceinline__ float sigf(float x) { return 1.0f / (1.0f + expf(-x)); }

// ---------------- agent-scope (cross-XCD coherent) access helpers ----------------
__device__ __forceinline__ float agl(const float* p) {
  return __hip_atomic_load(p, __ATOMIC_RELAXED, __HIP_MEMORY_SCOPE_AGENT);
}
__device__ __forceinline__ void ags(float* p, float v) {
  __hip_atomic_store(p, v, __ATOMIC_RELAXED, __HIP_MEMORY_SCOPE_AGENT);
}

// Hand-rolled grid barrier: 2-level monotonic counter tree, relaxed agent atomics
// only — NO acquire/release fence, so no L2 invalidate / writeback ever executes.
__device__ __forceinline__ void gsync(uint32* bar, unsigned bep) {
  __syncthreads();
  if (threadIdx.x == 0) {
    asm volatile("s_waitcnt vmcnt(0)" ::: "memory");
    uint32* leaf = bar + (blockIdx.x >> 5) * 32;   // 8 leaves x 32 blocks, line-spaced
    uint32* root = bar + 256;
    uint32 prev = __hip_atomic_fetch_add(leaf, 1u, __ATOMIC_RELAXED, __HIP_MEMORY_SCOPE_AGENT);
    if (prev + 1u == 32u * bep)
      __hip_atomic_fetch_add(root, 1u, __ATOMIC_RELAXED, __HIP_MEMORY_SCOPE_AGENT);
    int spins = 0;
    while (__hip_atomic_load(root, __ATOMIC_RELAXED, __HIP_MEMORY_SCOPE_AGENT) < 8u * bep) {
      __builtin_amdgcn_s_sleep(2);
      if (++spins > 20000000) break;   // safety valve: fail instead of hang
    }
  }
  __syncthreads();
}

// sum over each 16-lane row via DPP (VALU pipe, no LDS)
__device__ __forceinline__ float rowsum16(float v) {
  int vi;
  vi = __float_as_int(v);
  v += __int_as_float(__builtin_amdgcn_update_dpp(0, vi, 0xB1, 0xF, 0xF, true));  // quad xor1
  vi = __float_as_int(v);
  v += __int_as_float(__builtin_amdgcn_update_dpp(0, vi, 0x4E, 0xF, 0xF, true));  // quad xor2
  vi = __float_as_int(v);
  v += __int_as_float(__builtin_amdgcn_update_dpp(0, vi, 0x124, 0xF, 0xF, true)); // row_ror:4
  vi = __float_as_int(v);
  v += __int_as_float(__builtin_amdgcn_update_dpp(0, vi, 0x128, 0xF, 0xF, true)); // row_ror:8
  return v;
}

// ---------------- prologue: LSTM weight packing (fp16, LDS-resident layouts) ----
__global__ __launch_bounds__(256) void k_pack_lstm2(
    const float* __restrict__ awih, const float* __restrict__ awhh,
    const float* __restrict__ dwih, const float* __restrict__ dwhh,
    uint32* __restrict__ wal, uint32* __restrict__ wdl, uint32* __restrict__ wdt)
{
  long gid = blockIdx.x * 256L + threadIdx.x;
  const long N1 = 3686400L, N2 = 4603904L, N3 = 655360L;
  if (gid < N1) {
    int blk = (int)(gid / 28800), rem = (int)(gid % 28800);
    int r2 = rem % 900;
    int ks = rem / 900;
    uint32 out = 0;
    if (r2 < 896) {
      int kq = r2 >> 4, rd = r2 & 15;
      int k = kq * 32 + ks;
      int rp0 = blk * 32 + 2 * rd, rp1 = rp0 + 1;
      int row0 = (rp0 & 3) * 1024 + (rp0 >> 2);
      int row1 = (rp1 & 3) * 1024 + (rp1 >> 2);
      float w0 = (k < 768) ? awih[(size_t)row0 * 768 + k] : awhh[(size_t)row0 * 1024 + k - 768];
      float w1 = (k < 768) ? awih[(size_t)row1 * 768 + k] : awhh[(size_t)row1 * 1024 + k - 768];
      __half2 h = __floats2half2_rn(w0, w1);
      out = *(uint32*)&h;
    }
    wal[gid] = out;
  } else if (gid < N1 + N2) {
    long g = gid - N1;
    int blk = (int)(g / 35968), rem = (int)(g % 35968);
    int r2 = rem % 1124;
    int ks = rem / 1124;
    uint32 out = 0;
    if (r2 < 1120) {
      int kq = r2 >> 4, rd = r2 & 15;
      int k = kq * 32 + ks;
      int rp0 = blk * 32 + 2 * rd, rp1 = rp0 + 1;
      int row0 = (rp0 & 3) * 1024 + (rp0 >> 2);
      int row1 = (rp1 & 3) * 1024 + (rp1 >> 2);
      float w0 = (k < 1536) ? dwih[(size_t)row0 * 1536 + k] : dwhh[(size_t)row0 * 1024 + k - 1536];
      float w1 = (k < 1536) ? dwih[(size_t)row1 * 1536 + k] : dwhh[(size_t)row1 * 1024 + k - 1536];
      __half2 h = __floats2half2_rn(w0, w1);
      out = *(uint32*)&h;
    }
    wdl[g] = out;
  } else if (gid < N1 + N2 + N3) {
    long g = gid - N1 - N2;
    int blk = (int)(g / 5120), rem = (int)(g % 5120);
    int rd2 = rem & 3, rg = (rem >> 2) & 3, ks = (rem >> 4) & 31, i = rem >> 9;
    int k = 2240 + 32 * i + ks;
    int r0 = rg * 8 + 2 * rd2;
    int rp0 = blk * 32 + r0, rp1 = rp0 + 1;
    int row0 = (rp0 & 3) * 1024 + (rp0 >> 2);
    int row1 = (rp1 & 3) * 1024 + (rp1 >> 2);
    float w0 = (k < 1536) ? dwih[(size_t)row0 * 1536 + k] : dwhh[(size_t)row0 * 1024 + k - 1536];
    float w1 = (k < 1536) ? dwih[(size_t)row1 * 1536 + k] : dwhh[(size_t)row1 * 1024 + k - 1536];
    __half2 h = __floats2half2_rn(w0, w1);
    wdt[g] = *(uint32*)&h;
  }
}

__global__ __launch_bounds__(256) void k_pack_small(
    const float* __restrict__ w1, const float* __restrict__ w2,
    const float* __restrict__ mw, const float* __restrict__ pw,
    const float* __restrict__ abih, const float* __restrict__ abhh,
    const float* __restrict__ dbih, const float* __restrict__ dbhh,
    const float* __restrict__ lw, const float* __restrict__ cw,
    float* __restrict__ w1t, float* __restrict__ w2t, float* __restrict__ mt,
    float* __restrict__ pjt, float* __restrict__ ba, float* __restrict__ bd,
    float* __restrict__ lc)
{
  int gid = blockIdx.x * 256 + threadIdx.x;
  if (gid < 20480) { int k = gid / 256, j = gid % 256; w1t[gid] = w1[j * 80 + k]; return; }
  gid -= 20480;
  if (gid < 65536) { int k = gid / 256, j = gid % 256; w2t[gid] = w2[j * 256 + k]; return; }
  gid -= 65536;
  if (gid < 65536) { int e = gid / 128, d = gid % 128; mt[gid] = mw[d * 512 + e]; return; }
  gid -= 65536;
  if (gid < 122880) { int k = gid / 80, m = gid % 80; pjt[gid] = pw[m * 1536 + k]; return; }
  gid -= 122880;
  if (gid < 4096) { int j = gid >> 2, g = gid & 3, row = g * 1024 + j; ba[gid] = abih[row] + abhh[row]; return; }
  gid -= 4096;
  if (gid < 4096) { int j = gid >> 2, g = gid & 3, row = g * 1024 + j; bd[gid] = dbih[row] + dbhh[row]; return; }
  gid -= 4096;
  if (gid < 7936) {
    int c = gid / (31 * 128), rem = gid % (31 * 128);
    int kk = rem / 128, d = rem % 128;
    float s = 0.f;
    for (int f = 0; f < 32; ++f) s += lw[d * 32 + f] * cw[(f * 2 + c) * 31 + kk];
    lc[gid] = s;
  }
}

// ---------------- prologue: prenet (verified) ----------------
__global__ __launch_bounds__(256) void k_prenet(
    const float* __restrict__ targets, const float* __restrict__ w1t,
    const float* __restrict__ b1, const float* __restrict__ w2t,
    const float* __restrict__ b2, float* __restrict__ pn)
{
  int t = blockIdx.x, tid = threadIdx.x;
  __shared__ float X[32][80];
  __shared__ float h1[256][33];
  for (int i = tid; i < 2560; i += 256) {
    int b = i / 80, m = i % 80;
    X[b][m] = (t == 0) ? 0.f : targets[((size_t)b * TD_ + (t - 1)) * NM_ + m];
  }
  __syncthreads();
  int j = tid;
  float bj = b1[j];
  for (int bt = 0; bt < 4; ++bt) {
    float acc[8];
#pragma unroll
    for (int i = 0; i < 8; ++i) acc[i] = bj;
    for (int k = 0; k < 80; ++k) {
      float w = w1t[k * 256 + j];
#pragma unroll
      for (int i = 0; i < 8; ++i) acc[i] += w * X[bt * 8 + i][k];
    }
#pragma unroll
    for (int i = 0; i < 8; ++i) h1[j][bt * 8 + i] = fmaxf(acc[i], 0.f);
  }
  __syncthreads();
  float cj = b2[j];
  float* out = pn + (size_t)t * PRE_ * B_;
  for (int bt = 0; bt < 4; ++bt) {
    float acc[8];
#pragma unroll
    for (int i = 0; i < 8; ++i) acc[i] = cj;
    for (int k = 0; k < 256; ++k) {
      float w = w2t[k * 256 + j];
#pragma unroll
      for (int i = 0; i < 8; ++i) acc[i] += w * h1[k][bt * 8 + i];
    }
#pragma unroll
    for (int i = 0; i < 8; ++i) out[j * 32 + bt * 8 + i] = fmaxf(acc[i], 0.f);
  }
}

// ---------------- prologue: processed_enc (verified) ----------------
__global__ __launch_bounds__(256) void k_penc(
    const float* __restrict__ enc, const float* __restrict__ mt,
    float* __restrict__ penc)
{
  int t = blockIdx.x, tid = threadIdx.x;
  __shared__ float encL[32][256];
  __shared__ float red[128][8][2];
  int d = tid & 127, s = tid >> 7;
  float acc[4][8];
#pragma unroll
  for (int bt = 0; bt < 4; ++bt)
#pragma unroll
    for (int i = 0; i < 8; ++i) acc[bt][i] = 0.f;
  for (int eh = 0; eh < 2; ++eh) {
    for (int i = tid; i < 8192; i += 256) {
      int b = i >> 8, e = i & 255;
      encL[b][e] = enc[((size_t)b * TE_ + t) * EH_ + eh * 256 + e];
    }
    __syncthreads();
    for (int bt = 0; bt < 4; ++bt) {
      for (int el = s * 128; el < s * 128 + 128; ++el) {
        float w = mt[(eh * 256 + el) * 128 + d];
#pragma unroll
        for (int i = 0; i < 8; ++i) acc[bt][i] += w * encL[bt * 8 + i][el];
      }
    }
    __syncthreads();
  }
  for (int bt = 0; bt < 4; ++bt) {
#pragma unroll
    for (int i = 0; i < 8; ++i) red[d][i][s] = acc[bt][i];
    __syncthreads();
    if (s == 0) {
#pragma unroll
      for (int i = 0; i < 8; ++i)
        penc[((size_t)t * AD_ + d) * 32 + bt * 8 + i] = red[d][i][0] + red[d][i][1];
    }
    __syncthreads();
  }
}

// ---------------- prologue: enc transpose to fp16 [b][e][t] ----------------
__global__ __launch_bounds__(256) void k_enct(
    const float* __restrict__ enc, __half* __restrict__ enct)
{
  int blk = blockIdx.x, tid = threadIdx.x;
  int b = blk >> 6, t0 = ((blk >> 3) & 7) * 64, e0 = (blk & 7) * 64;
  __shared__ float tile[64][65];
  for (int i = 0; i < 16; ++i) {
    int tl = i * 4 + (tid >> 6), e = tid & 63;
    tile[tl][e] = enc[((size_t)b * TE_ + t0 + tl) * EH_ + e0 + e];
  }
  __syncthreads();
  for (int i = 0; i < 16; ++i) {
    int el = i * 4 + (tid >> 6), tl = tid & 63;
    enct[((size_t)b * EH_ + e0 + el) * TE_ + t0 + tl] = __float2half(tile[tl][el]);
  }
}

// ---------------- persistent step kernel ----------------
struct KP {
  const uint32* wal; const uint32* wdl; const uint4* wdt;
  const float* pn; const float* penc; const __half* enct;
  const float* qw; const float* ww; const float* pjt; const float* pjb;
  const float* lc; const float* ba; const float* bd;
  float* ahv; float* ac; float* dhv; float* dc; float* ctxv;
  float* awv; float* awsv;
  float* enp; float* mel; float* align;
  uint32* bar; int pv;
};

__device__ __forceinline__ void fma2(uint4 wv, const float* __restrict__ XC,
                                     int xb, float* acc)
{
  const __half2* hp = (const __half2*)&wv;
  float w[8];
#pragma unroll
  for (int d = 0; d < 4; ++d) {
    float2 f = __half22float2(hp[d]);
    w[2 * d] = f.x; w[2 * d + 1] = f.y;
  }
  float4 xa = *(const float4*)&XC[xb];
  float4 xc2 = *(const float4*)&XC[xb + 4];
  float x[8] = {xa.x, xa.y, xa.z, xa.w, xc2.x, xc2.y, xc2.z, xc2.w};
#pragma unroll
  for (int ri = 0; ri < 8; ++ri)
#pragma unroll
    for (int bi = 0; bi < 8; ++bi)
      acc[ri * 8 + bi] = fmaf(w[ri], x[bi], acc[ri * 8 + bi]);
}

__device__ __forceinline__ void lstm_finish(
    float* acc, float* __restrict__ GT, const float* __restrict__ bias,
    float* __restrict__ cst, float* __restrict__ hout,
    int rp0, int tid, int ks, int bq, int rg)
{
#pragma unroll
  for (int i = 0; i < 64; ++i) {
    float v = rowsum16(acc[i]);
    acc[i] = v + __shfl_xor(v, 16);
  }
  if (ks == 0) {
#pragma unroll
    for (int ri = 0; ri < 8; ++ri) {
      *(float4*)&GT[(rg * 8 + ri) * 32 + bq * 8] =
          make_float4(acc[ri * 8 + 0], acc[ri * 8 + 1], acc[ri * 8 + 2], acc[ri * 8 + 3]);
      *(float4*)&GT[(rg * 8 + ri) * 32 + bq * 8 + 4] =
          make_float4(acc[ri * 8 + 4], acc[ri * 8 + 5], acc[ri * 8 + 6], acc[ri * 8 + 7]);
    }
  }
  __syncthreads();
  if (tid < 256) {
    int jl = tid >> 5, b = tid & 31;
    float gi = GT[(jl * 4 + 0) * 32 + b] + bias[rp0 + jl * 4 + 0];
    float gf = GT[(jl * 4 + 1) * 32 + b] + bias[rp0 + jl * 4 + 1];
    float gg = GT[(jl * 4 + 2) * 32 + b] + bias[rp0 + jl * 4 + 2];
    float go = GT[(jl * 4 + 3) * 32 + b] + bias[rp0 + jl * 4 + 3];
    int j = (rp0 >> 2) + jl;
    float c0 = cst[j * 32 + b];                 // block-private: plain cached r/w
    float c2 = sigf(gf) * c0 + sigf(gi) * tanhf(gg);
    float h2 = sigf(go) * tanhf(c2);
    cst[j * 32 + b] = c2;
    ags(&hout[j * 32 + b], h2);                 // communicated: write-through to L3
  }
}

// A-LSTM: 28 chunks, depth-2 register prefetch (named regs, fully static).
__device__ __forceinline__ void run_lstm_a(const KP& p, int t,
    const float* __restrict__ ah_in, const float* __restrict__ ctx_in,
    float* __restrict__ ah_out,
    uint32* WlU, float* XC, float* GT, int tid, int ks, int bq, int rg,
    int kidx, int b4, int blk)
{
  float acc[64];
#pragma unroll
  for (int i = 0; i < 64; ++i) acc[i] = 0.f;
  const float* xp0 = p.pn + (size_t)t * 8192;
  const int wb = ks * 900 + rg * 4;
  const int xr = ks * 36 + bq * 8;
  auto srcA = [&](int kg) -> const float* {
    return (kg < 256) ? xp0 + (size_t)kg * 32
         : (kg < 768) ? ctx_in + (size_t)(kg - 256) * 32
                      : ah_in + (size_t)(kg - 768) * 32;
  };
  float4 st0 = *(const float4*)(srcA(kidx) + b4);
  float4 st1 = *(const float4*)(srcA(64 + kidx) + b4);
  for (int cb = 0; cb < 28; cb += 2) {
    __syncthreads();
    *(float4*)&XC[kidx * 36 + b4] = st0;
    __syncthreads();
    if (cb + 2 < 28) st0 = *(const float4*)(srcA((cb + 2) * 64 + kidx) + b4);
    fma2(*(const uint4*)&WlU[wb + (2 * cb) * 16], XC, xr, acc);
    fma2(*(const uint4*)&WlU[wb + (2 * cb + 1) * 16], XC, xr + 32 * 36, acc);
    __syncthreads();
    *(float4*)&XC[kidx * 36 + b4] = st1;
    __syncthreads();
    if (cb + 3 < 28) st1 = *(const float4*)(srcA((cb + 3) * 64 + kidx) + b4);
    fma2(*(const uint4*)&WlU[wb + (2 * cb + 2) * 16], XC, xr, acc);
    fma2(*(const uint4*)&WlU[wb + (2 * cb + 3) * 16], XC, xr + 32 * 36, acc);
  }
  lstm_finish(acc, GT, p.ba, p.ac, ah_out, blk * 32, tid, ks, bq, rg);
}

// D-LSTM: 40 chunks; 0..31 in a depth-2 loop, 32..39 static. Tail weights
// (chunks 35..39) stream from global wdt with pair prefetch — no resident wt[].
__device__ __forceinline__ void run_lstm_d(const KP& p,
    const float* __restrict__ xp0, const float* __restrict__ xp1,
    const float* __restrict__ xp2, float* __restrict__ dh_w,
    uint32* WlU, float* XC, float* GT,
    int tid, int ks, int bq, int rg, int kidx, int b4, int blk)
{
  float acc[64];
#pragma unroll
  for (int i = 0; i < 64; ++i) acc[i] = 0.f;
  const int wb = ks * 1124 + rg * 4;
  const int xr = ks * 36 + bq * 8;
  auto srcD = [&](int kg) -> const float* {
    return (kg < 1024) ? xp0 + (size_t)kg * 32
         : (kg < 1536) ? xp1 + (size_t)(kg - 1024) * 32
                       : xp2 + (size_t)(kg - 1536) * 32;
  };
  float4 st0 = *(const float4*)(srcD(kidx) + b4);
  float4 st1 = *(const float4*)(srcD(64 + kidx) + b4);
  for (int cb = 0; cb < 32; cb += 2) {
    __syncthreads();
    *(float4*)&XC[kidx * 36 + b4] = st0;
    __syncthreads();
    st0 = *(const float4*)(srcD((cb + 2) * 64 + kidx) + b4);   // cb+2 <= 33 < 40
    fma2(*(const uint4*)&WlU[wb + (2 * cb) * 16], XC, xr, acc);
    fma2(*(const uint4*)&WlU[wb + (2 * cb + 1) * 16], XC, xr + 32 * 36, acc);
    __syncthreads();
    *(float4*)&XC[kidx * 36 + b4] = st1;
    __syncthreads();
    st1 = *(const float4*)(srcD((cb + 3) * 64 + kidx) + b4);   // cb+3 <= 33
    fma2(*(const uint4*)&WlU[wb + (2 * cb + 2) * 16], XC, xr, acc);
    fma2(*(const uint4*)&WlU[wb + (2 * cb + 3) * 16], XC, xr + 32 * 36, acc);
  }
  // st0 = chunk 32, st1 = chunk 33. Static chunks 32..39.
  const uint4* wg = p.wdt + (size_t)(blk - 128) * 1280;
  const int wi = ks * 4 + rg;
  uint4 twA0, twB0, twA1, twB1;
  // chunk 32
  __syncthreads(); *(float4*)&XC[kidx * 36 + b4] = st0; __syncthreads();
  st0 = *(const float4*)(srcD(34 * 64 + kidx) + b4);
  twA0 = wg[0 * 128 + wi]; twB0 = wg[1 * 128 + wi];     // chunk35 pair
  fma2(*(const uint4*)&WlU[wb + 64 * 16], XC, xr, acc);
  fma2(*(const uint4*)&WlU[wb + 65 * 16], XC, xr + 32 * 36, acc);
  // chunk 33
  __syncthreads(); *(float4*)&XC[kidx * 36 + b4] = st1; __syncthreads();
  st1 = *(const float4*)(srcD(35 * 64 + kidx) + b4);
  twA1 = wg[2 * 128 + wi]; twB1 = wg[3 * 128 + wi];     // chunk36 pair
  fma2(*(const uint4*)&WlU[wb + 66 * 16], XC, xr, acc);
  fma2(*(const uint4*)&WlU[wb + 67 * 16], XC, xr + 32 * 36, acc);
  // chunk 34
  __syncthreads(); *(float4*)&XC[kidx * 36 + b4] = st0; __syncthreads();
  st0 = *(const float4*)(srcD(36 * 64 + kidx) + b4);
  fma2(*(const uint4*)&WlU[wb + 68 * 16], XC, xr, acc);
  fma2(*(const uint4*)&WlU[wb + 69 * 16], XC, xr + 32 * 36, acc);
  // chunk 35
  __syncthreads(); *(float4*)&XC[kidx * 36 + b4] = st1; __syncthreads();
  st1 = *(const float4*)(srcD(37 * 64 + kidx) + b4);
  fma2(twA0, XC, xr, acc); fma2(twB0, XC, xr + 32 * 36, acc);
  twA0 = wg[4 * 128 + wi]; twB0 = wg[5 * 128 + wi];     // chunk37 pair
  // chunk 36
  __syncthreads(); *(float4*)&XC[kidx * 36 + b4] = st0; __syncthreads();
  st0 = *(const float4*)(srcD(38 * 64 + kidx) + b4);
  fma2(twA1, XC, xr, acc); fma2(twB1, XC, xr + 32 * 36, acc);
  twA1 = wg[6 * 128 + wi]; twB1 = wg[7 * 128 + wi];     // chunk38 pair
  // chunk 37
  __syncthreads(); *(float4*)&XC[kidx * 36 + b4] = st1; __syncthreads();
  st1 = *(const float4*)(srcD(39 * 64 + kidx) + b4);
  fma2(twA0, XC, xr, acc); fma2(twB0, XC, xr + 32 * 36, acc);
  twA0 = wg[8 * 128 + wi]; twB0 = wg[9 * 128 + wi];     // chunk39 pair
  // chunk 38
  __syncthreads(); *(float4*)&XC[kidx * 36 + b4] = st0; __syncthreads();
  fma2(twA1, XC, xr, acc); fma2(twB1, XC, xr + 32 * 36, acc);
  // chunk 39
  __syncthreads(); *(float4*)&XC[kidx * 36 + b4] = st1; __syncthreads();
  fma2(twA0, XC, xr, acc); fma2(twB0, XC, xr + 32 * 36, acc);
  lstm_finish(acc, GT, p.bd, p.dc, dh_w, (blk - 128) * 32, tid, ks, bq, rg);
}

__device__ __forceinline__ void mel_block(
    const float* __restrict__ dhp, const float* __restrict__ ctp,
    const float* __restrict__ pjt, const float* __restrict__ pjb,
    float* __restrict__ mel, int bb, int tt, float* S, int tid)
{
  float* xo = S + 1536;
  float* ro = S + 3072;
  for (int i = tid; i < 1536; i += 512)
    xo[i] = (i < 1024) ? dhp[i * 32 + bb] : ctp[(i - 1024) * 32 + bb];
  __syncthreads();
  if (tid < 480) {
    int m = tid % 80, k2 = tid / 80;
    float a2 = 0.f;
    for (int k = k2 * 256; k < k2 * 256 + 256; ++k) a2 += pjt[k * 80 + m] * xo[k];
    ro[m * 8 + k2] = a2;
  }
  __syncthreads();
  if (tid < 80) {
    float s3 = pjb[tid];
#pragma unroll
    for (int k = 0; k < 6; ++k) s3 += ro[tid * 8 + k];
    mel[((size_t)bb * TD_ + tt) * NM_ + tid] = s3;
  }
}

__global__ __launch_bounds__(512) void k_step(KP p)
{
  extern __shared__ float LDSF[];
  const int blk = blockIdx.x, tid = threadIdx.x;
  const int ks = tid & 31, bq = (tid >> 5) & 3, rg = tid >> 7;
  const int kidx = tid >> 3, b4 = (tid & 7) * 4;
  const bool isA = blk < 128;
  float* SC = LDSF + (isA ? 28800 : 35968);
  float* XC = SC;
  float* GT = SC + 2304;
  uint32* WlU = (uint32*)LDSF;
  unsigned bep = 0;

  // one-time: weights into LDS
  {
    const uint32* src = isA ? p.wal + (size_t)blk * 28800
                            : p.wdl + (size_t)(blk - 128) * 35968;
    int n4 = isA ? 7200 : 8992;
    for (int i = tid; i < n4; i += 512)
      ((uint4*)WlU)[i] = ((const uint4*)src)[i];
  }
  __syncthreads();

  for (int t = 0; t < TD_; ++t) {
    // version slots: slot ver(s)=s%pv holds state INPUT to step s (written at s-1)
    const int vc = t % p.pv;
    const int vn = (t + 1) % p.pv;
    const int vp = (t > 0) ? (t - 1) % p.pv : 0;
    const float* ah_in  = p.ahv + (size_t)vc * 32768;
    float*       ah_out = p.ahv + (size_t)vn * 32768;
    const float* ctx_in = p.ctxv + (size_t)vc * 16384;
    float*       ctx_out= p.ctxv + (size_t)vn * 16384;

    // ---- PA: lstm_a(t) [0..127] || lstm_d(t-1) [128..255] ----
    if (isA) {
      run_lstm_a(p, t, ah_in, ctx_in, ah_out, WlU, XC, GT, tid, ks, bq, rg, kidx, b4, blk);
    } else if (t > 0) {
      run_lstm_d(p, ah_in, ctx_in,
                 p.dhv + (size_t)vp * 32768, p.dhv + (size_t)vc * 32768,
                 WlU, XC, GT, tid, ks, bq, rg, kidx, b4, blk);
    }
    bep += 1; gsync(p.bar, bep);
    // ---- PB: q (from ah slot vn) + location conv + energies ----
    {
      int tc = blk >> 3, ds = blk & 7;
      int t0 = tc * 16, d0 = ds * 16;
      float* qs  = SC;            // 512
      float* wws = SC + 512;      // 16
      float* AHC = SC + 528;      // 2048 (chunk buffer, later reused by win/lcs)
      float* win = SC + 528;      // 2944
      float* lcs = SC + 528 + 2944; // 992

      // early issue: win (versioned plain), lcs, penc, ww — into registers
      const float* awsrc  = p.awv  + (size_t)vc * 16384;
      const float* awssrc = p.awsv + (size_t)vc * 16384;
      float winr[6];
#pragma unroll
      for (int k = 0; k < 6; ++k) {
        int i = tid + k * 512;
        float v = 0.f;
        if (i < 2944) {
          int c = i / 1472, r = (i >> 5) % 46, bbw = i & 31;
          int tg = t0 - 15 + r;
          if (tg >= 0 && tg < 512) v = (c ? awssrc : awsrc)[tg * 32 + bbw];
        }
        winr[k] = v;
      }
      float lcr[2];
#pragma unroll
      for (int k = 0; k < 2; ++k) {
        int i = tid + k * 512;
        lcr[k] = 0.f;
        if (i < 992) {
          int c = i / 496, kk = (i >> 4) % 31, dl2 = i & 15;
          lcr[k] = p.lc[(c * 31 + kk) * 128 + d0 + dl2];
        }
      }
      const int bbE = tid & 31, thE = tid >> 5;
      const int ttE = t0 + thE;
      float pencr[16];
#pragma unroll
      for (int dl2 = 0; dl2 < 16; ++dl2)
        pencr[dl2] = p.penc[((size_t)ttE * 128 + d0 + dl2) * 32 + bbE];
      float wwr = (tid < 16) ? p.ww[d0 + tid] : 0.f;

      // q: 16-chunk LDS-staged matvec, depth-2 prefetch
      int bb2 = tid & 31, dl = tid >> 5;
      const float* ahsrc = p.ahv + (size_t)vn * 32768;
      const float* qbase = p.qw + (size_t)(d0 + dl) * 1024;
      float qacc = 0.f;
      float4 sq0 = *(const float4*)(ahsrc + 0 * 2048 + tid * 4);
      float4 sq1 = *(const float4*)(ahsrc + 1 * 2048 + tid * 4);
      for (int cb = 0; cb < 16; cb += 2) {
        __syncthreads();
        *(float4*)(AHC + tid * 4) = sq0;
        __syncthreads();
        if (cb + 2 < 16) sq0 = *(const float4*)(ahsrc + (cb + 2) * 2048 + tid * 4);
        {
          const float* qrow = qbase + cb * 64;
#pragma unroll
          for (int jj = 0; jj < 64; jj += 4) {
            float4 qv = *(const float4*)(qrow + jj);
            qacc = fmaf(qv.x, AHC[(jj + 0) * 32 + bb2], qacc);
            qacc = fmaf(qv.y, AHC[(jj + 1) * 32 + bb2], qacc);
            qacc = fmaf(qv.z, AHC[(jj + 2) * 32 + bb2], qacc);
            qacc = fmaf(qv.w, AHC[(jj + 3) * 32 + bb2], qacc);
          }
        }
        __syncthreads();
        *(float4*)(AHC + tid * 4) = sq1;
        __syncthreads();
        if (cb + 3 < 16) sq1 = *(const float4*)(ahsrc + (cb + 3) * 2048 + tid * 4);
        {
          const float* qrow = qbase + (cb + 1) * 64;
#pragma unroll
          for (int jj = 0; jj < 64; jj += 4) {
            float4 qv = *(const float4*)(qrow + jj);
            qacc = fmaf(qv.x, AHC[(jj + 0) * 32 + bb2], qacc);
            qacc = fmaf(qv.y, AHC[(jj + 1) * 32 + bb2], qacc);
            qacc = fmaf(qv.z, AHC[(jj + 2) * 32 + bb2], qacc);
            qacc = fmaf(qv.w, AHC[(jj + 3) * 32 + bb2], qacc);
          }
        }
      }
      __syncthreads();
      qs[dl * 32 + bb2] = qacc;
      if (tid < 16) wws[tid] = wwr;
#pragma unroll
      for (int k = 0; k < 6; ++k) { int i = tid + k * 512; if (i < 2944) win[i] = winr[k]; }
#pragma unroll
      for (int k = 0; k < 2; ++k) { int i = tid + k * 512; if (i < 992) lcs[i] = lcr[k]; }
      __syncthreads();
      {
        float pa[16];
#pragma unroll
        for (int i = 0; i < 16; ++i) pa[i] = 0.f;
        for (int c = 0; c < 2; ++c) {
          for (int kk = 0; kk < 31; ++kk) {
            float wv = win[c * 1472 + (thE + kk) * 32 + bbE];
            const float4* lr = (const float4*)(lcs + c * 496 + kk * 16);
            float4 l0 = lr[0], l1 = lr[1], l2 = lr[2], l3 = lr[3];
            pa[0]  += l0.x * wv; pa[1]  += l0.y * wv; pa[2]  += l0.z * wv; pa[3]  += l0.w * wv;
            pa[4]  += l1.x * wv; pa[5]  += l1.y * wv; pa[6]  += l1.z * wv; pa[7]  += l1.w * wv;
            pa[8]  += l2.x * wv; pa[9]  += l2.y * wv; pa[10] += l2.z * wv; pa[11] += l2.w * wv;
            pa[12] += l3.x * wv; pa[13] += l3.y * wv; pa[14] += l3.z * wv; pa[15] += l3.w * wv;
          }
        }
        float epv = 0.f;
#pragma unroll
        for (int dl2 = 0; dl2 < 16; ++dl2) {
          float v = qs[dl2 * 32 + bbE] + pencr[dl2] + pa[dl2];
          epv += wws[dl2] * tanhf(v);
        }
        ags(&p.enp[(size_t)bbE * 4096 + ttE * 8 + ds], epv);
      }
    }
    bep += 1; gsync(p.bar, bep);
    // ---- PC: softmax + ctx (+aw/aws/align, +mel(t-1)) ----
    {
      int bb = blk >> 3, et = blk & 7;
      float* awL = SC + 512;
      float* cr  = SC + 1024;
      // early: prefetch the enct tile into registers (before softmax)
      int el = tid & 63, ts = tid >> 6;
      const uint32* eb = (const uint32*)(p.enct +
          ((size_t)(bb * 512 + et * 64 + el)) * 512 + ts * 64);
      uint32 ebr[32];
#pragma unroll
      for (int i = 0; i < 32; ++i) ebr[i] = eb[i];
      const float* epb = p.enp + (size_t)bb * 4096 + tid * 8;
      float e = agl(epb) + agl(epb + 1) + agl(epb + 2) + agl(epb + 3)
              + agl(epb + 4) + agl(epb + 5) + agl(epb + 6) + agl(epb + 7);
      // softmax: wave shfl reduce + 8-wave LDS combine (2 barriers total)
      float m = e;
#pragma unroll
      for (int k = 1; k < 64; k <<= 1) m = fmaxf(m, __shfl_xor(m, k));
      int wv = tid >> 6;
      if ((tid & 63) == 0) SC[wv] = m;
      __syncthreads();
      m = SC[0];
#pragma unroll
      for (int k = 1; k < 8; ++k) m = fmaxf(m, SC[k]);
      float x = expf(e - m);
      float s = x;
#pragma unroll
      for (int k = 1; k < 64; k <<= 1) s += __shfl_xor(s, k);
      if ((tid & 63) == 0) SC[8 + wv] = s;
      __syncthreads();
      s = SC[8];
#pragma unroll
      for (int k = 1; k < 8; ++k) s += SC[8 + k];
      float a = x * (1.f / s);
      awL[tid] = a;
      __syncthreads();
      float acc = 0.f;
#pragma unroll
      for (int i = 0; i < 32; ++i) {
        float2 f = __half22float2(*(const __half2*)&ebr[i]);
        acc += awL[ts * 64 + 2 * i] * f.x + awL[ts * 64 + 2 * i + 1] * f.y;
      }
      cr[ts * 64 + el] = acc;
      __syncthreads();
      if (tid < 64) {
        float s2 = 0.f;
#pragma unroll
        for (int k = 0; k < 8; ++k) s2 += cr[k * 64 + tid];
        ags(&ctx_out[(et * 64 + tid) * 32 + bb], s2);
      }
      if (et == 0) {
        float osv = p.awsv[(size_t)vc * 16384 + tid * 32 + bb];  // self-written at t-1
        ags(&p.awv[(size_t)vn * 16384 + tid * 32 + bb], a);
        ags(&p.awsv[(size_t)vn * 16384 + tid * 32 + bb], osv + a);
        p.align[((size_t)bb * TD_ + t) * TE_ + tid] = a;
      }
      if (et == 1 && t > 0) {
        mel_block(p.dhv + (size_t)vc * 32768, p.ctxv + (size_t)vc * 16384,
                  p.pjt, p.pjb, p.mel, bb, t - 1, SC, tid);
      }
    }
    bep += 1; gsync(p.bar, bep);
  }
  // ---- epilogue: lstm_d(511) then mel(511) ----
  {
    const int v511 = 511 % p.pv, v512 = 512 % p.pv;
    if (!isA) {
      run_lstm_d(p, p.ahv + (size_t)v512 * 32768, p.ctxv + (size_t)v512 * 16384,
                 p.dhv + (size_t)v511 * 32768, p.dhv + (size_t)v512 * 32768,
                 WlU, XC, GT, tid, ks, bq, rg, kidx, b4, blk);
    }
    bep += 1; gsync(p.bar, bep);
    if (blk < 32) {
      mel_block(p.dhv + (size_t)v512 * 32768, p.ctxv + (size_t)v512 * 16384,
                p.pjt, p.pjb, p.mel, blk, 511, SC, tid);
    }
  }
}

extern "C" void kernel_launch(void* const* d_in, const int* in_sizes, int n_in,
                              void* d_out, int out_size, void* d_ws, size_t ws_size,
                              hipStream_t stream)
{
  const float* enc     = (const float*)d_in[0];
  const float* targets = (const float*)d_in[1];
  const float* pw1  = (const float*)d_in[2];
  const float* pb1  = (const float*)d_in[3];
  const float* pw2  = (const float*)d_in[4];
  const float* pb2  = (const float*)d_in[5];
  const float* mw   = (const float*)d_in[6];
  const float* qw   = (const float*)d_in[7];
  const float* www  = (const float*)d_in[8];
  const float* lw   = (const float*)d_in[9];
  const float* cw   = (const float*)d_in[10];
  const float* awih = (const float*)d_in[11];
  const float* awhh = (const float*)d_in[12];
  const float* abih = (const float*)d_in[13];
  const float* abhh = (const float*)d_in[14];
  const float* dwih = (const float*)d_in[15];
  const float* dwhh = (const float*)d_in[16];
  const float* dbih = (const float*)d_in[17];
  const float* dbhh = (const float*)d_in[18];
  const float* pjw  = (const float*)d_in[19];
  const float* pjb  = (const float*)d_in[20];

  uint32* wsb = (uint32*)d_ws;
  size_t o = 0;
  auto F = [&](size_t n) { size_t r = o; o += n; return r; };
  size_t oWAL = F(3686400), oWDL = F(4603904), oWDT = F(655360);
  size_t oENCT = F(4194304);           // 8,388,608 halfs
  size_t oPN = F(4194304), oPENC = F(2097152);
  size_t oW1T = F(20480), oW2T = F(65536), oMT = F(65536), oPJT = F(122880);
  size_t oLC = F(7936), oBA = F(4096), oBD = F(4096);
  size_t oZR = o;                      // zeroed region start
  size_t oAC = F(32768), oDC = F(32768), oBAR = F(1024);
  size_t zr_dw = o - oZR;
  o = (o + 31) & ~(size_t)31;          // 128B-align versioned space
  size_t fixed_dw = o;
  size_t avail_dw = ws_size / 4;
  // slot = ah 32768 + dh 32768 + ctx 16384 + aw 16384 + aws 16384 = 114688 dw
  long pvl = (avail_dw > fixed_dw) ? (long)((avail_dw - fixed_dw) / 114688) : 0;
  int pv = (pvl < 3) ? 3 : (pvl > 513 ? 513 : (int)pvl);
  size_t oAHV  = F((size_t)pv * 32768);
  size_t oDHV  = F((size_t)pv * 32768);
  size_t oCTXV = F((size_t)pv * 16384);
  size_t oAWV  = F((size_t)pv * 16384);
  size_t oAWSV = F((size_t)pv * 16384);
  size_t oENP  = oW1T;                 // alias: 131,072 <= 151,552 (W1T+W2T+MT)

  hipMemsetAsync(wsb + oZR, 0, zr_dw * 4, stream);
  hipMemsetAsync(wsb + oAHV, 0, (size_t)32768 * 4, stream);
  hipMemsetAsync(wsb + oDHV, 0, (size_t)32768 * 4, stream);
  hipMemsetAsync(wsb + oCTXV, 0, (size_t)16384 * 4, stream);
  hipMemsetAsync(wsb + oAWV, 0, (size_t)16384 * 4, stream);
  hipMemsetAsync(wsb + oAWSV, 0, (size_t)16384 * 4, stream);

  float* mel = (float*)d_out;
  float* align = mel + (size_t)B_ * TD_ * NM_;

  k_pack_lstm2<<<34944, 256, 0, stream>>>(awih, awhh, dwih, dwhh,
                                          wsb + oWAL, wsb + oWDL, wsb + oWDT);
  k_pack_small<<<1135, 256, 0, stream>>>(pw1, pw2, mw, pjw, abih, abhh, dbih, dbhh,
                                         lw, cw,
                                         (float*)(wsb + oW1T), (float*)(wsb + oW2T),
                                         (float*)(wsb + oMT), (float*)(wsb + oPJT),
                                         (float*)(wsb + oBA), (float*)(wsb + oBD),
                                         (float*)(wsb + oLC));
  k_prenet<<<512, 256, 0, stream>>>(targets, (float*)(wsb + oW1T), pb1,
                                    (float*)(wsb + oW2T), pb2, (float*)(wsb + oPN));
  k_penc<<<512, 256, 0, stream>>>(enc, (float*)(wsb + oMT), (float*)(wsb + oPENC));
  k_enct<<<2048, 256, 0, stream>>>(enc, (__half*)(wsb + oENCT));

  KP kp;
  kp.wal = wsb + oWAL; kp.wdl = wsb + oWDL; kp.wdt = (const uint4*)(wsb + oWDT);
  kp.pn = (float*)(wsb + oPN); kp.penc = (float*)(wsb + oPENC);
  kp.enct = (__half*)(wsb + oENCT);
  kp.qw = qw; kp.ww = www; kp.pjt = (float*)(wsb + oPJT); kp.pjb = pjb;
  kp.lc = (float*)(wsb + oLC); kp.ba = (float*)(wsb + oBA); kp.bd = (float*)(wsb + oBD);
  kp.ahv = (float*)(wsb + oAHV); kp.ac = (float*)(wsb + oAC);
  kp.dhv = (float*)(wsb + oDHV); kp.dc = (float*)(wsb + oDC);
  kp.ctxv = (float*)(wsb + oCTXV);
  kp.awv = (float*)(wsb + oAWV); kp.awsv = (float*)(wsb + oAWSV);
  kp.enp = (float*)(wsb + oENP); kp.mel = mel; kp.align = align;
  kp.bar = wsb + oBAR; kp.pv = pv;

  hipFuncSetAttribute((const void*)k_step,
                      hipFuncAttributeMaxDynamicSharedMemorySize, 161728);
  void* kargs[] = { &kp };
  hipLaunchCooperativeKernel((const void*)k_step, dim3(256), dim3(512), kargs,
                             161728, stream);
}